// Round 1
// baseline (646.932 us; speedup 1.0000x reference)
//
#include <hip/hip_runtime.h>
#include <math.h>

#define NP 4096
#define KNN 6

__device__ inline double det3(const double M[3][3]) {
  return M[0][0]*(M[1][1]*M[2][2]-M[1][2]*M[2][1])
       - M[0][1]*(M[1][0]*M[2][2]-M[1][2]*M[2][0])
       + M[0][2]*(M[1][0]*M[2][1]-M[1][1]*M[2][0]);
}

// K1: means + cross-covariance (block reduce) -> 3x3 SVD (thread 0, double Jacobi)
//     -> rigid_recon = R*pc + t written SoA to ws.
__global__ __launch_bounds__(256) void k1_kabsch(const float* __restrict__ in,
                                                 const float* __restrict__ sf,
                                                 float* __restrict__ rx,
                                                 float* __restrict__ ry,
                                                 float* __restrict__ rz) {
  const int tid = threadIdx.x;
  double acc[15];
#pragma unroll
  for (int q = 0; q < 15; ++q) acc[q] = 0.0;
  for (int i = tid; i < NP; i += 256) {
    double px = in[i], py = in[NP + i], pz = in[2*NP + i];
    double qx = px + (double)sf[i];
    double qy = py + (double)sf[NP + i];
    double qz = pz + (double)sf[2*NP + i];
    acc[0] += px; acc[1] += py; acc[2] += pz;
    acc[3] += qx; acc[4] += qy; acc[5] += qz;
    acc[6] += px*qx; acc[7]  += px*qy; acc[8]  += px*qz;
    acc[9] += py*qx; acc[10] += py*qy; acc[11] += py*qz;
    acc[12]+= pz*qx; acc[13] += pz*qy; acc[14] += pz*qz;
  }
  __shared__ double red[256];
  __shared__ double tot[15];
  for (int q = 0; q < 15; ++q) {
    red[tid] = acc[q];
    __syncthreads();
    for (int s = 128; s > 0; s >>= 1) {
      if (tid < s) red[tid] += red[tid + s];
      __syncthreads();
    }
    if (tid == 0) tot[q] = red[0];
    __syncthreads();
  }
  __shared__ float Rs[9];
  __shared__ float ts[3];
  if (tid == 0) {
    const double invN = 1.0 / (double)NP;
    double cp[3] = { tot[0]*invN, tot[1]*invN, tot[2]*invN };
    double cr[3] = { tot[3]*invN, tot[4]*invN, tot[5]*invN };
    double H[3][3];
    for (int a = 0; a < 3; ++a)
      for (int b = 0; b < 3; ++b)
        H[a][b] = tot[6 + a*3 + b] - (double)NP * cp[a] * cr[b];
    // A = H^T H (symmetric PSD); Jacobi eigendecomposition -> V, lambda = sigma^2
    double A[3][3];
    for (int a = 0; a < 3; ++a)
      for (int b = 0; b < 3; ++b)
        A[a][b] = H[0][a]*H[0][b] + H[1][a]*H[1][b] + H[2][a]*H[2][b];
    double V[3][3] = {{1,0,0},{0,1,0},{0,0,1}};
    const int PQ[3][2] = {{0,1},{0,2},{1,2}};
    for (int sweep = 0; sweep < 20; ++sweep) {
      for (int r = 0; r < 3; ++r) {
        const int p = PQ[r][0], q = PQ[r][1];
        double apq = A[p][q];
        if (fabs(apq) > 1e-300) {
          double theta = (A[q][q] - A[p][p]) / (2.0 * apq);
          double tt = copysign(1.0, theta) / (fabs(theta) + sqrt(theta*theta + 1.0));
          double c = 1.0 / sqrt(tt*tt + 1.0);
          double s = tt * c;
          for (int k = 0; k < 3; ++k) { double akp=A[k][p], akq=A[k][q]; A[k][p]=c*akp - s*akq; A[k][q]=s*akp + c*akq; }
          for (int k = 0; k < 3; ++k) { double apk=A[p][k], aqk=A[q][k]; A[p][k]=c*apk - s*aqk; A[q][k]=s*apk + c*aqk; }
          for (int k = 0; k < 3; ++k) { double vkp=V[k][p], vkq=V[k][q]; V[k][p]=c*vkp - s*vkq; V[k][q]=s*vkp + c*vkq; }
        }
      }
    }
    int ord[3] = {0,1,2};
    for (int a = 0; a < 2; ++a)
      for (int b = a + 1; b < 3; ++b)
        if (A[ord[b]][ord[b]] > A[ord[a]][ord[a]]) { int t2 = ord[a]; ord[a] = ord[b]; ord[b] = t2; }
    double Vc[3][3], Uc[3][3];
    for (int j = 0; j < 3; ++j) {
      const int e = ord[j];
      double lam = A[e][e] > 0.0 ? A[e][e] : 0.0;
      double sv = sqrt(lam);
      double isv = sv > 0.0 ? 1.0 / sv : 0.0;
      for (int a = 0; a < 3; ++a) Vc[a][j] = V[a][e];
      for (int a = 0; a < 3; ++a)
        Uc[a][j] = (H[a][0]*Vc[0][j] + H[a][1]*Vc[1][j] + H[a][2]*Vc[2][j]) * isv;
    }
    double dd = (det3(Uc) * det3(Vc)) >= 0.0 ? 1.0 : -1.0;
    double R[3][3];
    for (int a = 0; a < 3; ++a)
      for (int b = 0; b < 3; ++b)
        R[a][b] = Vc[a][0]*Uc[b][0] + Vc[a][1]*Uc[b][1] + dd * Vc[a][2]*Uc[b][2];
    double tv[3];
    for (int a = 0; a < 3; ++a)
      tv[a] = cr[a] - (R[a][0]*cp[0] + R[a][1]*cp[1] + R[a][2]*cp[2]);
    for (int a = 0; a < 3; ++a) {
      Rs[a*3+0] = (float)R[a][0];
      Rs[a*3+1] = (float)R[a][1];
      Rs[a*3+2] = (float)R[a][2];
      ts[a] = (float)tv[a];
    }
  }
  __syncthreads();
  for (int i = tid; i < NP; i += 256) {
    float px = in[i], py = in[NP + i], pz = in[2*NP + i];
    rx[i] = Rs[0]*px + Rs[1]*py + Rs[2]*pz + ts[0];
    ry[i] = Rs[3]*px + Rs[4]*py + Rs[5]*pz + ts[1];
    rz[i] = Rs[6]*px + Rs[7]*py + Rs[8]*pz + ts[2];
  }
}

// K2: blocks 0..15 scan the rigid cloud (self-kNN), blocks 16..31 scan y cloud.
// One center per thread; register top-6 insertion; output = sum of 6 neighbor coords.
// (The -6*center terms cancel in laplace_x - laplace_y, so sums suffice.)
__global__ __launch_bounds__(256) void k2_knn(const float* __restrict__ rx,
                                              const float* __restrict__ ry,
                                              const float* __restrict__ rz,
                                              const float* __restrict__ ycloud,
                                              float* __restrict__ xs0, float* __restrict__ xs1, float* __restrict__ xs2,
                                              float* __restrict__ ys0, float* __restrict__ ys1, float* __restrict__ ys2) {
  __shared__ float sx[NP], sy[NP], sz[NP];  // 48 KB
  const int tid = threadIdx.x;
  const bool isX = blockIdx.x < 16;
  const int cb = blockIdx.x & 15;
  if (isX) {
    for (int i = tid; i < NP; i += 256) { sx[i] = rx[i]; sy[i] = ry[i]; sz[i] = rz[i]; }
  } else {
    for (int i = tid; i < NP; i += 256) { sx[i] = ycloud[i]; sy[i] = ycloud[NP + i]; sz[i] = ycloud[2*NP + i]; }
  }
  __syncthreads();
  const int i = cb * 256 + tid;
  const float cx = rx[i], cy = ry[i], cz = rz[i];
  float bd[KNN];
  int   bi[KNN];
#pragma unroll
  for (int k = 0; k < KNN; ++k) { bd[k] = 3.4e38f; bi[k] = 0; }
  for (int j = 0; j < NP; ++j) {
    float dx = sx[j] - cx, dy = sy[j] - cy, dz = sz[j] - cz;
    float d2 = dx*dx + dy*dy + dz*dz;
    if (d2 < bd[KNN-1]) {
      int pos = KNN - 1;
      while (pos > 0 && bd[pos-1] > d2) {
        bd[pos] = bd[pos-1]; bi[pos] = bi[pos-1]; --pos;
      }
      bd[pos] = d2; bi[pos] = j;
    }
  }
  float s0 = 0.f, s1 = 0.f, s2 = 0.f;
#pragma unroll
  for (int k = 0; k < KNN; ++k) { s0 += sx[bi[k]]; s1 += sy[bi[k]]; s2 += sz[bi[k]]; }
  if (isX) { xs0[i] = s0; xs1[i] = s1; xs2[i] = s2; }
  else     { ys0[i] = s0; ys1[i] = s1; ys2[i] = s2; }
}

// K3: mean laplace diff + L1 loss, single block, deterministic tree reduce.
__global__ __launch_bounds__(256) void k3_final(const float* __restrict__ rx,
                                                const float* __restrict__ ry,
                                                const float* __restrict__ rz,
                                                const float* __restrict__ xs0, const float* __restrict__ xs1, const float* __restrict__ xs2,
                                                const float* __restrict__ ys0, const float* __restrict__ ys1, const float* __restrict__ ys2,
                                                const float* __restrict__ pred,
                                                float* __restrict__ out) {
  const int tid = threadIdx.x;
  double a[3] = {0.0, 0.0, 0.0};
  for (int i = tid; i < NP; i += 256) {
    a[0] += (double)(xs0[i] - ys0[i]);
    a[1] += (double)(xs1[i] - ys1[i]);
    a[2] += (double)(xs2[i] - ys2[i]);
  }
  __shared__ double red[256];
  __shared__ double mres[3];
  for (int q = 0; q < 3; ++q) {
    red[tid] = a[q];
    __syncthreads();
    for (int s = 128; s > 0; s >>= 1) {
      if (tid < s) red[tid] += red[tid + s];
      __syncthreads();
    }
    // mean over N of (diff/5):
    if (tid == 0) mres[q] = red[0] * (0.2 / (double)NP);
    __syncthreads();
  }
  const float m0 = (float)mres[0], m1 = (float)mres[1], m2 = (float)mres[2];
  double s = 0.0;
  for (int i = tid; i < NP; i += 256) {
    s += (double)fabsf(rx[i] - m0 - pred[i]);
    s += (double)fabsf(ry[i] - m1 - pred[NP + i]);
    s += (double)fabsf(rz[i] - m2 - pred[2*NP + i]);
  }
  red[tid] = s;
  __syncthreads();
  for (int st = 128; st > 0; st >>= 1) {
    if (tid < st) red[tid] += red[tid + st];
    __syncthreads();
  }
  if (tid == 0) out[0] = (float)(red[0] / (3.0 * (double)NP));
}

extern "C" void kernel_launch(void* const* d_in, const int* in_sizes, int n_in,
                              void* d_out, int out_size, void* d_ws, size_t ws_size,
                              hipStream_t stream) {
  const float* in   = (const float*)d_in[0];
  const float* sf   = (const float*)d_in[1];
  const float* y1   = (const float*)d_in[2];
  const float* pred = (const float*)d_in[3];
  float* ws = (float*)d_ws;
  float* rx  = ws + 0*NP;
  float* ry  = ws + 1*NP;
  float* rz  = ws + 2*NP;
  float* xs0 = ws + 3*NP;
  float* xs1 = ws + 4*NP;
  float* xs2 = ws + 5*NP;
  float* ys0 = ws + 6*NP;
  float* ys1 = ws + 7*NP;
  float* ys2 = ws + 8*NP;

  k1_kabsch<<<1, 256, 0, stream>>>(in, sf, rx, ry, rz);
  k2_knn<<<32, 256, 0, stream>>>(rx, ry, rz, y1, xs0, xs1, xs2, ys0, ys1, ys2);
  k3_final<<<1, 256, 0, stream>>>(rx, ry, rz, xs0, xs1, xs2, ys0, ys1, ys2, pred,
                                  (float*)d_out);
}

// Round 2
// 149.220 us; speedup vs baseline: 4.3354x; 4.3354x over previous
//
#include <hip/hip_runtime.h>
#include <math.h>

#define NP 4096
#define KNN 6
#define NCHUNK 16
#define CHUNK 256   // NP / NCHUNK

typedef unsigned long long u64;

__device__ inline double det3(const double M[3][3]) {
  return M[0][0]*(M[1][1]*M[2][2]-M[1][2]*M[2][1])
       - M[0][1]*(M[1][0]*M[2][2]-M[1][2]*M[2][0])
       + M[0][2]*(M[1][0]*M[2][1]-M[1][1]*M[2][0]);
}

__device__ inline double wave_reduce(double v) {
#pragma unroll
  for (int o = 32; o > 0; o >>= 1) v += __shfl_down(v, o);
  return v;
}

// K1: means + cross-covariance (shuffle block reduce) -> 3x3 SVD (thread 0,
// double Jacobi) -> rigid_recon = R*pc + t written SoA to ws.
__global__ __launch_bounds__(256) void k1_kabsch(const float* __restrict__ in,
                                                 const float* __restrict__ sf,
                                                 float* __restrict__ rx,
                                                 float* __restrict__ ry,
                                                 float* __restrict__ rz) {
  const int tid = threadIdx.x;
  const int lane = tid & 63, wv = tid >> 6;
  double acc[15];
#pragma unroll
  for (int q = 0; q < 15; ++q) acc[q] = 0.0;
  for (int i = tid; i < NP; i += 256) {
    double px = in[i], py = in[NP + i], pz = in[2*NP + i];
    double qx = px + (double)sf[i];
    double qy = py + (double)sf[NP + i];
    double qz = pz + (double)sf[2*NP + i];
    acc[0] += px; acc[1] += py; acc[2] += pz;
    acc[3] += qx; acc[4] += qy; acc[5] += qz;
    acc[6] += px*qx; acc[7]  += px*qy; acc[8]  += px*qz;
    acc[9] += py*qx; acc[10] += py*qy; acc[11] += py*qz;
    acc[12]+= pz*qx; acc[13] += pz*qy; acc[14] += pz*qz;
  }
  __shared__ double wred[4][15];
#pragma unroll
  for (int q = 0; q < 15; ++q) {
    double v = wave_reduce(acc[q]);
    if (lane == 0) wred[wv][q] = v;
  }
  __syncthreads();
  __shared__ float Rs[9];
  __shared__ float ts[3];
  if (tid == 0) {
    double tot[15];
    for (int q = 0; q < 15; ++q)
      tot[q] = wred[0][q] + wred[1][q] + wred[2][q] + wred[3][q];
    const double invN = 1.0 / (double)NP;
    double cp[3] = { tot[0]*invN, tot[1]*invN, tot[2]*invN };
    double cr[3] = { tot[3]*invN, tot[4]*invN, tot[5]*invN };
    double H[3][3];
    for (int a = 0; a < 3; ++a)
      for (int b = 0; b < 3; ++b)
        H[a][b] = tot[6 + a*3 + b] - (double)NP * cp[a] * cr[b];
    double A[3][3];
    for (int a = 0; a < 3; ++a)
      for (int b = 0; b < 3; ++b)
        A[a][b] = H[0][a]*H[0][b] + H[1][a]*H[1][b] + H[2][a]*H[2][b];
    double V[3][3] = {{1,0,0},{0,1,0},{0,0,1}};
    const int PQ[3][2] = {{0,1},{0,2},{1,2}};
    for (int sweep = 0; sweep < 12; ++sweep) {
      for (int r = 0; r < 3; ++r) {
        const int p = PQ[r][0], q = PQ[r][1];
        double apq = A[p][q];
        if (fabs(apq) > 1e-300) {
          double theta = (A[q][q] - A[p][p]) / (2.0 * apq);
          double tt = copysign(1.0, theta) / (fabs(theta) + sqrt(theta*theta + 1.0));
          double c = 1.0 / sqrt(tt*tt + 1.0);
          double s = tt * c;
          for (int k = 0; k < 3; ++k) { double akp=A[k][p], akq=A[k][q]; A[k][p]=c*akp - s*akq; A[k][q]=s*akp + c*akq; }
          for (int k = 0; k < 3; ++k) { double apk=A[p][k], aqk=A[q][k]; A[p][k]=c*apk - s*aqk; A[q][k]=s*apk + c*aqk; }
          for (int k = 0; k < 3; ++k) { double vkp=V[k][p], vkq=V[k][q]; V[k][p]=c*vkp - s*vkq; V[k][q]=s*vkp + c*vkq; }
        }
      }
    }
    int ord[3] = {0,1,2};
    for (int a = 0; a < 2; ++a)
      for (int b = a + 1; b < 3; ++b)
        if (A[ord[b]][ord[b]] > A[ord[a]][ord[a]]) { int t2 = ord[a]; ord[a] = ord[b]; ord[b] = t2; }
    double Vc[3][3], Uc[3][3];
    for (int j = 0; j < 3; ++j) {
      const int e = ord[j];
      double lam = A[e][e] > 0.0 ? A[e][e] : 0.0;
      double sv = sqrt(lam);
      double isv = sv > 0.0 ? 1.0 / sv : 0.0;
      for (int a = 0; a < 3; ++a) Vc[a][j] = V[a][e];
      for (int a = 0; a < 3; ++a)
        Uc[a][j] = (H[a][0]*Vc[0][j] + H[a][1]*Vc[1][j] + H[a][2]*Vc[2][j]) * isv;
    }
    double dd = (det3(Uc) * det3(Vc)) >= 0.0 ? 1.0 : -1.0;
    double R[3][3];
    for (int a = 0; a < 3; ++a)
      for (int b = 0; b < 3; ++b)
        R[a][b] = Vc[a][0]*Uc[b][0] + Vc[a][1]*Uc[b][1] + dd * Vc[a][2]*Uc[b][2];
    double tv[3];
    for (int a = 0; a < 3; ++a)
      tv[a] = cr[a] - (R[a][0]*cp[0] + R[a][1]*cp[1] + R[a][2]*cp[2]);
    for (int a = 0; a < 3; ++a) {
      Rs[a*3+0] = (float)R[a][0];
      Rs[a*3+1] = (float)R[a][1];
      Rs[a*3+2] = (float)R[a][2];
      ts[a] = (float)tv[a];
    }
  }
  __syncthreads();
  for (int i = tid; i < NP; i += 256) {
    float px = in[i], py = in[NP + i], pz = in[2*NP + i];
    rx[i] = Rs[0]*px + Rs[1]*py + Rs[2]*pz + ts[0];
    ry[i] = Rs[3]*px + Rs[4]*py + Rs[5]*pz + ts[1];
    rz[i] = Rs[6]*px + Rs[7]*py + Rs[8]*pz + ts[2];
  }
}

// K2a: partial top-6 per (cloud, ref-chunk, center). Grid (NCHUNK, 16, 2).
// Each thread owns one center, scans a 256-candidate LDS-staged ref chunk,
// writes its sorted top-6 as packed u64 keys (f32bits(d2)<<32 | global_idx).
__global__ __launch_bounds__(256) void k2_partial(const float* __restrict__ rx,
                                                  const float* __restrict__ ry,
                                                  const float* __restrict__ rz,
                                                  const float* __restrict__ ycloud,
                                                  u64* __restrict__ part) {
  __shared__ float sx[CHUNK], sy[CHUNK], sz[CHUNK];
  const int tid = threadIdx.x;
  const int chunk = blockIdx.x;   // ref chunk
  const int cblk  = blockIdx.y;   // center block
  const int cloud = blockIdx.z;   // 0 = rigid (self), 1 = y
  const int j0 = chunk * CHUNK;
  if (cloud == 0) {
    sx[tid] = rx[j0 + tid]; sy[tid] = ry[j0 + tid]; sz[tid] = rz[j0 + tid];
  } else {
    sx[tid] = ycloud[j0 + tid];
    sy[tid] = ycloud[NP + j0 + tid];
    sz[tid] = ycloud[2*NP + j0 + tid];
  }
  __syncthreads();
  const int ci = cblk * 256 + tid;
  const float cx = rx[ci], cy = ry[ci], cz = rz[ci];
  float bd[KNN];
  int   bi[KNN];
#pragma unroll
  for (int k = 0; k < KNN; ++k) { bd[k] = 3.4e38f; bi[k] = 0; }
  for (int j = 0; j < CHUNK; ++j) {
    float dx = sx[j] - cx, dy = sy[j] - cy, dz = sz[j] - cz;
    float d2 = dx*dx + dy*dy + dz*dz;
    if (d2 < bd[KNN-1]) {
      int pos = KNN - 1;
      while (pos > 0 && bd[pos-1] > d2) {
        bd[pos] = bd[pos-1]; bi[pos] = bi[pos-1]; --pos;
      }
      bd[pos] = d2; bi[pos] = j;
    }
  }
  u64* o = part + ((size_t)((cloud * NCHUNK + chunk) * NP + ci)) * KNN;
#pragma unroll
  for (int k = 0; k < KNN; ++k)
    o[k] = ((u64)__float_as_uint(bd[k]) << 32) | (u64)(bi[k] + j0);
}

// K2b: merge the 16 sorted 6-lists per center for both clouds, gather the
// neighbor coords, and block-reduce the laplace-diff sums. Grid = 16 blocks.
__global__ __launch_bounds__(256) void k2_merge(const u64* __restrict__ part,
                                                const float* __restrict__ rx,
                                                const float* __restrict__ ry,
                                                const float* __restrict__ rz,
                                                const float* __restrict__ ycloud,
                                                double* __restrict__ blockpart) {
  const int tid = threadIdx.x;
  const int lane = tid & 63, wv = tid >> 6;
  const int ci = blockIdx.x * 256 + tid;
  double d0, d1, d2s;
  {
    u64 bk[KNN];
#pragma unroll
    for (int k = 0; k < KNN; ++k) bk[k] = ~0ULL;
    const u64* base = part + (size_t)ci * KNN;               // cloud 0
    for (int c = 0; c < NCHUNK; ++c) {
      const u64* p = base + (size_t)c * NP * KNN;
#pragma unroll
      for (int e = 0; e < KNN; ++e) {
        u64 k = p[e];
        if (k >= bk[KNN-1]) break;
        int pos = KNN - 1;
        while (pos > 0 && bk[pos-1] > k) { bk[pos] = bk[pos-1]; --pos; }
        bk[pos] = k;
      }
    }
    float s0 = 0.f, s1 = 0.f, s2 = 0.f;
#pragma unroll
    for (int k = 0; k < KNN; ++k) {
      int idx = (int)(bk[k] & 0xFFFFFFFFu);
      s0 += rx[idx]; s1 += ry[idx]; s2 += rz[idx];
    }
    d0 = s0; d1 = s1; d2s = s2;
  }
  {
    u64 bk[KNN];
#pragma unroll
    for (int k = 0; k < KNN; ++k) bk[k] = ~0ULL;
    const u64* base = part + ((size_t)NCHUNK * NP + ci) * KNN;  // cloud 1
    for (int c = 0; c < NCHUNK; ++c) {
      const u64* p = base + (size_t)c * NP * KNN;
#pragma unroll
      for (int e = 0; e < KNN; ++e) {
        u64 k = p[e];
        if (k >= bk[KNN-1]) break;
        int pos = KNN - 1;
        while (pos > 0 && bk[pos-1] > k) { bk[pos] = bk[pos-1]; --pos; }
        bk[pos] = k;
      }
    }
    float s0 = 0.f, s1 = 0.f, s2 = 0.f;
#pragma unroll
    for (int k = 0; k < KNN; ++k) {
      int idx = (int)(bk[k] & 0xFFFFFFFFu);
      s0 += ycloud[idx]; s1 += ycloud[NP + idx]; s2 += ycloud[2*NP + idx];
    }
    d0 -= s0; d1 -= s1; d2s -= s2;
  }
  __shared__ double wred[4][3];
  double v0 = wave_reduce(d0), v1 = wave_reduce(d1), v2 = wave_reduce(d2s);
  if (lane == 0) { wred[wv][0] = v0; wred[wv][1] = v1; wred[wv][2] = v2; }
  __syncthreads();
  if (tid == 0) {
    blockpart[blockIdx.x * 3 + 0] = wred[0][0] + wred[1][0] + wred[2][0] + wred[3][0];
    blockpart[blockIdx.x * 3 + 1] = wred[0][1] + wred[1][1] + wred[2][1] + wred[3][1];
    blockpart[blockIdx.x * 3 + 2] = wred[0][2] + wred[1][2] + wred[2][2] + wred[3][2];
  }
}

// K3: finish mean laplace diff, then L1 loss (single block, shuffle reduce).
__global__ __launch_bounds__(256) void k3_final(const double* __restrict__ blockpart,
                                                const float* __restrict__ rx,
                                                const float* __restrict__ ry,
                                                const float* __restrict__ rz,
                                                const float* __restrict__ pred,
                                                float* __restrict__ out) {
  const int tid = threadIdx.x;
  const int lane = tid & 63, wv = tid >> 6;
  __shared__ float m[3];
  if (tid == 0) {
    double s0 = 0.0, s1 = 0.0, s2 = 0.0;
    for (int b = 0; b < 16; ++b) {
      s0 += blockpart[b*3 + 0];
      s1 += blockpart[b*3 + 1];
      s2 += blockpart[b*3 + 2];
    }
    const double sc = 0.2 / (double)NP;   // /(k-1) then mean over N
    m[0] = (float)(s0 * sc); m[1] = (float)(s1 * sc); m[2] = (float)(s2 * sc);
  }
  __syncthreads();
  const float m0 = m[0], m1 = m[1], m2 = m[2];
  double s = 0.0;
  for (int i = tid; i < NP; i += 256) {
    s += (double)fabsf(rx[i] - m0 - pred[i]);
    s += (double)fabsf(ry[i] - m1 - pred[NP + i]);
    s += (double)fabsf(rz[i] - m2 - pred[2*NP + i]);
  }
  __shared__ double wred[4];
  double v = wave_reduce(s);
  if (lane == 0) wred[wv] = v;
  __syncthreads();
  if (tid == 0)
    out[0] = (float)((wred[0] + wred[1] + wred[2] + wred[3]) / (3.0 * (double)NP));
}

extern "C" void kernel_launch(void* const* d_in, const int* in_sizes, int n_in,
                              void* d_out, int out_size, void* d_ws, size_t ws_size,
                              hipStream_t stream) {
  const float* in   = (const float*)d_in[0];
  const float* sf   = (const float*)d_in[1];
  const float* y1   = (const float*)d_in[2];
  const float* pred = (const float*)d_in[3];

  u64* part = (u64*)d_ws;                                    // 2*16*4096*6 u64 = 6.29 MB
  double* blockpart = (double*)(part + (size_t)2 * NCHUNK * NP * KNN);  // 16*3 doubles
  float* rx = (float*)(blockpart + 48);
  float* ry = rx + NP;
  float* rz = ry + NP;

  k1_kabsch<<<1, 256, 0, stream>>>(in, sf, rx, ry, rz);
  k2_partial<<<dim3(NCHUNK, 16, 2), 256, 0, stream>>>(rx, ry, rz, y1, part);
  k2_merge<<<16, 256, 0, stream>>>(part, rx, ry, rz, y1, blockpart);
  k3_final<<<1, 256, 0, stream>>>(blockpart, rx, ry, rz, pred, (float*)d_out);
}

// Round 3
// 69.029 us; speedup vs baseline: 9.3719x; 2.1617x over previous
//
#include <hip/hip_runtime.h>
#include <math.h>

#define NP 4096
#define KNN 6
#define NCHUNK 16
#define CHUNK 256   // NP / NCHUNK

typedef unsigned int u32;

__device__ inline double det3(const double M[3][3]) {
  return M[0][0]*(M[1][1]*M[2][2]-M[1][2]*M[2][1])
       - M[0][1]*(M[1][0]*M[2][2]-M[1][2]*M[2][0])
       + M[0][2]*(M[1][0]*M[2][1]-M[1][1]*M[2][0]);
}

__device__ inline double wave_reduce(double v) {
#pragma unroll
  for (int o = 32; o > 0; o >>= 1) v += __shfl_down(v, o);
  return v;
}

// branchless sorted top-6 insert: b0<=b1<=...<=b5, key bubbles to its slot.
#define TOP6_INSERT(key)                                   \
  { u32 _t;                                                \
    _t = min(b0, key); key = max(b0, key); b0 = _t;        \
    _t = min(b1, key); key = max(b1, key); b1 = _t;        \
    _t = min(b2, key); key = max(b2, key); b2 = _t;        \
    _t = min(b3, key); key = max(b3, key); b3 = _t;        \
    _t = min(b4, key); key = max(b4, key); b4 = _t;        \
    _t = min(b5, key); key = max(b5, key); b5 = _t; }

// K1: means + cross-covariance (shuffle block reduce) -> 3x3 SVD (thread 0,
// double Jacobi) -> rigid_recon = R*pc + t written SoA to ws.
__global__ __launch_bounds__(256) void k1_kabsch(const float* __restrict__ in,
                                                 const float* __restrict__ sf,
                                                 float* __restrict__ rx,
                                                 float* __restrict__ ry,
                                                 float* __restrict__ rz) {
  const int tid = threadIdx.x;
  const int lane = tid & 63, wv = tid >> 6;
  double acc[15];
#pragma unroll
  for (int q = 0; q < 15; ++q) acc[q] = 0.0;
  for (int i = tid; i < NP; i += 256) {
    double px = in[i], py = in[NP + i], pz = in[2*NP + i];
    double qx = px + (double)sf[i];
    double qy = py + (double)sf[NP + i];
    double qz = pz + (double)sf[2*NP + i];
    acc[0] += px; acc[1] += py; acc[2] += pz;
    acc[3] += qx; acc[4] += qy; acc[5] += qz;
    acc[6] += px*qx; acc[7]  += px*qy; acc[8]  += px*qz;
    acc[9] += py*qx; acc[10] += py*qy; acc[11] += py*qz;
    acc[12]+= pz*qx; acc[13] += pz*qy; acc[14] += pz*qz;
  }
  __shared__ double wred[4][15];
#pragma unroll
  for (int q = 0; q < 15; ++q) {
    double v = wave_reduce(acc[q]);
    if (lane == 0) wred[wv][q] = v;
  }
  __syncthreads();
  __shared__ float Rs[9];
  __shared__ float ts[3];
  if (tid == 0) {
    double tot[15];
    for (int q = 0; q < 15; ++q)
      tot[q] = wred[0][q] + wred[1][q] + wred[2][q] + wred[3][q];
    const double invN = 1.0 / (double)NP;
    double cp[3] = { tot[0]*invN, tot[1]*invN, tot[2]*invN };
    double cr[3] = { tot[3]*invN, tot[4]*invN, tot[5]*invN };
    double H[3][3];
    for (int a = 0; a < 3; ++a)
      for (int b = 0; b < 3; ++b)
        H[a][b] = tot[6 + a*3 + b] - (double)NP * cp[a] * cr[b];
    double A[3][3];
    for (int a = 0; a < 3; ++a)
      for (int b = 0; b < 3; ++b)
        A[a][b] = H[0][a]*H[0][b] + H[1][a]*H[1][b] + H[2][a]*H[2][b];
    double V[3][3] = {{1,0,0},{0,1,0},{0,0,1}};
    const int PQ[3][2] = {{0,1},{0,2},{1,2}};
    for (int sweep = 0; sweep < 12; ++sweep) {
      for (int r = 0; r < 3; ++r) {
        const int p = PQ[r][0], q = PQ[r][1];
        double apq = A[p][q];
        if (fabs(apq) > 1e-300) {
          double theta = (A[q][q] - A[p][p]) / (2.0 * apq);
          double tt = copysign(1.0, theta) / (fabs(theta) + sqrt(theta*theta + 1.0));
          double c = 1.0 / sqrt(tt*tt + 1.0);
          double s = tt * c;
          for (int k = 0; k < 3; ++k) { double akp=A[k][p], akq=A[k][q]; A[k][p]=c*akp - s*akq; A[k][q]=s*akp + c*akq; }
          for (int k = 0; k < 3; ++k) { double apk=A[p][k], aqk=A[q][k]; A[p][k]=c*apk - s*aqk; A[q][k]=s*apk + c*aqk; }
          for (int k = 0; k < 3; ++k) { double vkp=V[k][p], vkq=V[k][q]; V[k][p]=c*vkp - s*vkq; V[k][q]=s*vkp + c*vkq; }
        }
      }
    }
    int ord[3] = {0,1,2};
    for (int a = 0; a < 2; ++a)
      for (int b = a + 1; b < 3; ++b)
        if (A[ord[b]][ord[b]] > A[ord[a]][ord[a]]) { int t2 = ord[a]; ord[a] = ord[b]; ord[b] = t2; }
    double Vc[3][3], Uc[3][3];
    for (int j = 0; j < 3; ++j) {
      const int e = ord[j];
      double lam = A[e][e] > 0.0 ? A[e][e] : 0.0;
      double sv = sqrt(lam);
      double isv = sv > 0.0 ? 1.0 / sv : 0.0;
      for (int a = 0; a < 3; ++a) Vc[a][j] = V[a][e];
      for (int a = 0; a < 3; ++a)
        Uc[a][j] = (H[a][0]*Vc[0][j] + H[a][1]*Vc[1][j] + H[a][2]*Vc[2][j]) * isv;
    }
    double dd = (det3(Uc) * det3(Vc)) >= 0.0 ? 1.0 : -1.0;
    double R[3][3];
    for (int a = 0; a < 3; ++a)
      for (int b = 0; b < 3; ++b)
        R[a][b] = Vc[a][0]*Uc[b][0] + Vc[a][1]*Uc[b][1] + dd * Vc[a][2]*Uc[b][2];
    double tv[3];
    for (int a = 0; a < 3; ++a)
      tv[a] = cr[a] - (R[a][0]*cp[0] + R[a][1]*cp[1] + R[a][2]*cp[2]);
    for (int a = 0; a < 3; ++a) {
      Rs[a*3+0] = (float)R[a][0];
      Rs[a*3+1] = (float)R[a][1];
      Rs[a*3+2] = (float)R[a][2];
      ts[a] = (float)tv[a];
    }
  }
  __syncthreads();
  for (int i = tid; i < NP; i += 256) {
    float px = in[i], py = in[NP + i], pz = in[2*NP + i];
    rx[i] = Rs[0]*px + Rs[1]*py + Rs[2]*pz + ts[0];
    ry[i] = Rs[3]*px + Rs[4]*py + Rs[5]*pz + ts[1];
    rz[i] = Rs[6]*px + Rs[7]*py + Rs[8]*pz + ts[2];
  }
}

// K2a: partial top-6 per (cloud, ref-chunk, center). Grid (NCHUNK, 16, 2).
// Branchless u32-key sorting network; keys = (f32bits(d2)&~0xFFF) | idx.
// Output planes part[((cloud*NCHUNK+chunk)*KNN + k)*NP + ci] for coalescing.
__global__ __launch_bounds__(256) void k2_partial(const float* __restrict__ rx,
                                                  const float* __restrict__ ry,
                                                  const float* __restrict__ rz,
                                                  const float* __restrict__ ycloud,
                                                  u32* __restrict__ part) {
  __shared__ float4 sc[CHUNK];
  const int tid = threadIdx.x;
  const int chunk = blockIdx.x;   // ref chunk
  const int cblk  = blockIdx.y;   // center block
  const int cloud = blockIdx.z;   // 0 = rigid (self), 1 = y
  const int j0 = chunk * CHUNK;
  if (cloud == 0) {
    sc[tid] = make_float4(rx[j0 + tid], ry[j0 + tid], rz[j0 + tid], 0.f);
  } else {
    sc[tid] = make_float4(ycloud[j0 + tid], ycloud[NP + j0 + tid],
                          ycloud[2*NP + j0 + tid], 0.f);
  }
  __syncthreads();
  const int ci = cblk * 256 + tid;
  const float cx = rx[ci], cy = ry[ci], cz = rz[ci];
  u32 b0 = ~0u, b1 = ~0u, b2 = ~0u, b3 = ~0u, b4 = ~0u, b5 = ~0u;
#pragma unroll 8
  for (int j = 0; j < CHUNK; ++j) {
    float4 c = sc[j];
    float dx = c.x - cx, dy = c.y - cy, dz = c.z - cz;
    float d2 = fmaf(dx, dx, fmaf(dy, dy, dz * dz));
    u32 key = (__float_as_uint(d2) & 0xFFFFF000u) | (u32)(j0 + j);
    TOP6_INSERT(key);
  }
  u32* o = part + (size_t)(cloud * NCHUNK + chunk) * KNN * NP + ci;
  o[0*NP] = b0; o[1*NP] = b1; o[2*NP] = b2;
  o[3*NP] = b3; o[4*NP] = b4; o[5*NP] = b5;
}

// K2b: fold the 16 partial 6-lists per center for both clouds (same branchless
// network), gather neighbor coords, block-reduce laplace-diff sums. 16 blocks.
__global__ __launch_bounds__(256) void k2_merge(const u32* __restrict__ part,
                                                const float* __restrict__ rx,
                                                const float* __restrict__ ry,
                                                const float* __restrict__ rz,
                                                const float* __restrict__ ycloud,
                                                double* __restrict__ blockpart) {
  const int tid = threadIdx.x;
  const int lane = tid & 63, wv = tid >> 6;
  const int ci = blockIdx.x * 256 + tid;
  double d0, d1, d2s;
  {
    u32 b0 = ~0u, b1 = ~0u, b2 = ~0u, b3 = ~0u, b4 = ~0u, b5 = ~0u;
    for (int c = 0; c < NCHUNK; ++c) {
      const u32* p = part + (size_t)c * KNN * NP + ci;   // cloud 0
#pragma unroll
      for (int e = 0; e < KNN; ++e) {
        u32 key = p[(size_t)e * NP];
        TOP6_INSERT(key);
      }
    }
    u32 bk[KNN] = { b0, b1, b2, b3, b4, b5 };
    float s0 = 0.f, s1 = 0.f, s2 = 0.f;
#pragma unroll
    for (int k = 0; k < KNN; ++k) {
      int idx = (int)(bk[k] & 0xFFFu);
      s0 += rx[idx]; s1 += ry[idx]; s2 += rz[idx];
    }
    d0 = s0; d1 = s1; d2s = s2;
  }
  {
    u32 b0 = ~0u, b1 = ~0u, b2 = ~0u, b3 = ~0u, b4 = ~0u, b5 = ~0u;
    for (int c = 0; c < NCHUNK; ++c) {
      const u32* p = part + (size_t)(NCHUNK + c) * KNN * NP + ci;  // cloud 1
#pragma unroll
      for (int e = 0; e < KNN; ++e) {
        u32 key = p[(size_t)e * NP];
        TOP6_INSERT(key);
      }
    }
    u32 bk[KNN] = { b0, b1, b2, b3, b4, b5 };
    float s0 = 0.f, s1 = 0.f, s2 = 0.f;
#pragma unroll
    for (int k = 0; k < KNN; ++k) {
      int idx = (int)(bk[k] & 0xFFFu);
      s0 += ycloud[idx]; s1 += ycloud[NP + idx]; s2 += ycloud[2*NP + idx];
    }
    d0 -= s0; d1 -= s1; d2s -= s2;
  }
  __shared__ double wred[4][3];
  double v0 = wave_reduce(d0), v1 = wave_reduce(d1), v2 = wave_reduce(d2s);
  if (lane == 0) { wred[wv][0] = v0; wred[wv][1] = v1; wred[wv][2] = v2; }
  __syncthreads();
  if (tid == 0) {
    blockpart[blockIdx.x * 3 + 0] = wred[0][0] + wred[1][0] + wred[2][0] + wred[3][0];
    blockpart[blockIdx.x * 3 + 1] = wred[0][1] + wred[1][1] + wred[2][1] + wred[3][1];
    blockpart[blockIdx.x * 3 + 2] = wred[0][2] + wred[1][2] + wred[2][2] + wred[3][2];
  }
}

// K3: finish mean laplace diff, then L1 loss (single block, shuffle reduce).
__global__ __launch_bounds__(256) void k3_final(const double* __restrict__ blockpart,
                                                const float* __restrict__ rx,
                                                const float* __restrict__ ry,
                                                const float* __restrict__ rz,
                                                const float* __restrict__ pred,
                                                float* __restrict__ out) {
  const int tid = threadIdx.x;
  const int lane = tid & 63, wv = tid >> 6;
  __shared__ float m[3];
  if (tid == 0) {
    double s0 = 0.0, s1 = 0.0, s2 = 0.0;
    for (int b = 0; b < 16; ++b) {
      s0 += blockpart[b*3 + 0];
      s1 += blockpart[b*3 + 1];
      s2 += blockpart[b*3 + 2];
    }
    const double sc = 0.2 / (double)NP;   // /(k-1) then mean over N
    m[0] = (float)(s0 * sc); m[1] = (float)(s1 * sc); m[2] = (float)(s2 * sc);
  }
  __syncthreads();
  const float m0 = m[0], m1 = m[1], m2 = m[2];
  double s = 0.0;
  for (int i = tid; i < NP; i += 256) {
    s += (double)fabsf(rx[i] - m0 - pred[i]);
    s += (double)fabsf(ry[i] - m1 - pred[NP + i]);
    s += (double)fabsf(rz[i] - m2 - pred[2*NP + i]);
  }
  __shared__ double wred[4];
  double v = wave_reduce(s);
  if (lane == 0) wred[wv] = v;
  __syncthreads();
  if (tid == 0)
    out[0] = (float)((wred[0] + wred[1] + wred[2] + wred[3]) / (3.0 * (double)NP));
}

extern "C" void kernel_launch(void* const* d_in, const int* in_sizes, int n_in,
                              void* d_out, int out_size, void* d_ws, size_t ws_size,
                              hipStream_t stream) {
  const float* in   = (const float*)d_in[0];
  const float* sf   = (const float*)d_in[1];
  const float* y1   = (const float*)d_in[2];
  const float* pred = (const float*)d_in[3];

  u32* part = (u32*)d_ws;                                  // 2*16*6*4096 u32 = 3.15 MB
  double* blockpart = (double*)(part + (size_t)2 * NCHUNK * KNN * NP);  // 16*3 doubles
  float* rx = (float*)(blockpart + 48);
  float* ry = rx + NP;
  float* rz = ry + NP;

  k1_kabsch<<<1, 256, 0, stream>>>(in, sf, rx, ry, rz);
  k2_partial<<<dim3(NCHUNK, 16, 2), 256, 0, stream>>>(rx, ry, rz, y1, part);
  k2_merge<<<16, 256, 0, stream>>>(part, rx, ry, rz, y1, blockpart);
  k3_final<<<1, 256, 0, stream>>>(blockpart, rx, ry, rz, pred, (float*)d_out);
}

// Round 4
// 56.143 us; speedup vs baseline: 11.5229x; 1.2295x over previous
//
#include <hip/hip_runtime.h>
#include <math.h>

#define NP 4096
#define KNN 6
#define NCHUNK 16
#define CHUNK 256   // NP / NCHUNK

typedef unsigned int u32;
typedef unsigned long long u64;

__device__ inline double wave_reduce(double v) {
#pragma unroll
  for (int o = 32; o > 0; o >>= 1) v += __shfl_down(v, o);
  return v;
}

__device__ inline float det3f(const float M[3][3]) {
  return M[0][0]*(M[1][1]*M[2][2]-M[1][2]*M[2][1])
       - M[0][1]*(M[1][0]*M[2][2]-M[1][2]*M[2][0])
       + M[0][2]*(M[1][0]*M[2][1]-M[1][1]*M[2][0]);
}

// ILP-friendly sorted top-6 insert: b_i' = min(b_i, max(b_{i-1}, key)).
// Dep chain = 2 (vs 12 for the bubble network), 11 VALU ops.
#define TOP6_INSERT_ILP(key)                                          \
  { u32 m0 = max(b0, key), m1 = max(b1, key), m2 = max(b2, key),      \
        m3 = max(b3, key), m4 = max(b4, key);                         \
    b0 = min(b0, key); b1 = min(b1, m0); b2 = min(b2, m1);            \
    b3 = min(b3, m2); b4 = min(b4, m3); b5 = min(b5, m4); }

// K1: f64 covariance reduce -> f32 Jacobi SVD (thread 0) -> writes R(9)+t(3)
// floats to ws and resets the finisher ticket counter.
__global__ __launch_bounds__(256) void k1_kabsch(const float* __restrict__ in,
                                                 const float* __restrict__ sf,
                                                 float* __restrict__ Rt,
                                                 u32* __restrict__ counter) {
  const int tid = threadIdx.x;
  const int lane = tid & 63, wv = tid >> 6;
  double acc[15];
#pragma unroll
  for (int q = 0; q < 15; ++q) acc[q] = 0.0;
  for (int i = tid; i < NP; i += 256) {
    double px = in[i], py = in[NP + i], pz = in[2*NP + i];
    double qx = px + (double)sf[i];
    double qy = py + (double)sf[NP + i];
    double qz = pz + (double)sf[2*NP + i];
    acc[0] += px; acc[1] += py; acc[2] += pz;
    acc[3] += qx; acc[4] += qy; acc[5] += qz;
    acc[6] += px*qx; acc[7]  += px*qy; acc[8]  += px*qz;
    acc[9] += py*qx; acc[10] += py*qy; acc[11] += py*qz;
    acc[12]+= pz*qx; acc[13] += pz*qy; acc[14] += pz*qz;
  }
  __shared__ double wred[4][15];
#pragma unroll
  for (int q = 0; q < 15; ++q) {
    double v = wave_reduce(acc[q]);
    if (lane == 0) wred[wv][q] = v;
  }
  __syncthreads();
  if (tid == 0) {
    double tot[15];
    for (int q = 0; q < 15; ++q)
      tot[q] = wred[0][q] + wred[1][q] + wred[2][q] + wred[3][q];
    const double invN = 1.0 / (double)NP;
    double cp[3] = { tot[0]*invN, tot[1]*invN, tot[2]*invN };
    double cr[3] = { tot[3]*invN, tot[4]*invN, tot[5]*invN };
    float H[3][3];
    for (int a = 0; a < 3; ++a)
      for (int b = 0; b < 3; ++b)
        H[a][b] = (float)(tot[6 + a*3 + b] - (double)NP * cp[a] * cr[b]);
    // A = H^T H, f32 Jacobi eigendecomposition -> V
    float A[3][3];
    for (int a = 0; a < 3; ++a)
      for (int b = 0; b < 3; ++b)
        A[a][b] = H[0][a]*H[0][b] + H[1][a]*H[1][b] + H[2][a]*H[2][b];
    float V[3][3] = {{1,0,0},{0,1,0},{0,0,1}};
    const int PQ[3][2] = {{0,1},{0,2},{1,2}};
    for (int sweep = 0; sweep < 8; ++sweep) {
      for (int r = 0; r < 3; ++r) {
        const int p = PQ[r][0], q = PQ[r][1];
        float apq = A[p][q];
        if (fabsf(apq) > 1e-30f) {
          float theta = (A[q][q] - A[p][p]) / (2.0f * apq);
          float tt = copysignf(1.0f, theta) / (fabsf(theta) + sqrtf(theta*theta + 1.0f));
          float c = 1.0f / sqrtf(tt*tt + 1.0f);
          float s = tt * c;
          for (int k = 0; k < 3; ++k) { float akp=A[k][p], akq=A[k][q]; A[k][p]=c*akp - s*akq; A[k][q]=s*akp + c*akq; }
          for (int k = 0; k < 3; ++k) { float apk=A[p][k], aqk=A[q][k]; A[p][k]=c*apk - s*aqk; A[q][k]=s*apk + c*aqk; }
          for (int k = 0; k < 3; ++k) { float vkp=V[k][p], vkq=V[k][q]; V[k][p]=c*vkp - s*vkq; V[k][q]=s*vkp + c*vkq; }
        }
      }
    }
    int ord[3] = {0,1,2};
    for (int a = 0; a < 2; ++a)
      for (int b = a + 1; b < 3; ++b)
        if (A[ord[b]][ord[b]] > A[ord[a]][ord[a]]) { int t2 = ord[a]; ord[a] = ord[b]; ord[b] = t2; }
    float Vc[3][3], Uc[3][3];
    for (int j = 0; j < 3; ++j) {
      const int e = ord[j];
      float lam = A[e][e] > 0.0f ? A[e][e] : 0.0f;
      float sv = sqrtf(lam);
      float isv = sv > 1e-20f ? 1.0f / sv : 0.0f;
      for (int a = 0; a < 3; ++a) Vc[a][j] = V[a][e];
      for (int a = 0; a < 3; ++a)
        Uc[a][j] = (H[a][0]*Vc[0][j] + H[a][1]*Vc[1][j] + H[a][2]*Vc[2][j]) * isv;
    }
    float dd = (det3f(Uc) * det3f(Vc)) >= 0.0f ? 1.0f : -1.0f;
    float R[3][3];
    for (int a = 0; a < 3; ++a)
      for (int b = 0; b < 3; ++b)
        R[a][b] = Vc[a][0]*Uc[b][0] + Vc[a][1]*Uc[b][1] + dd * Vc[a][2]*Uc[b][2];
    for (int a = 0; a < 3; ++a) {
      Rt[a*3+0] = R[a][0]; Rt[a*3+1] = R[a][1]; Rt[a*3+2] = R[a][2];
      Rt[9+a] = (float)(cr[a] - ((double)R[a][0]*cp[0] + (double)R[a][1]*cp[1]
                                 + (double)R[a][2]*cp[2]));
    }
    *counter = 0u;
  }
}

// K2: partial top-6 per (cloud, ref-chunk, center-block). Grid (16,16,2).
// Recon is computed in-kernel from R,t (no global round-trip); 16 designated
// blocks (cloud 0, chunk==cblk) materialize rx/ry/rz for the later gathers.
// Key = monotone-u32(|c|^2 - 2 c.x) truncated, low 12 bits = candidate index.
__global__ __launch_bounds__(256) void k2_scan(const float* __restrict__ in,
                                               const float* __restrict__ ycloud,
                                               const float* __restrict__ Rt,
                                               u32* __restrict__ part,
                                               float* __restrict__ rx,
                                               float* __restrict__ ry,
                                               float* __restrict__ rz) {
  __shared__ float4 sc[CHUNK];
  __shared__ float Rts[12];
  const int tid = threadIdx.x;
  const int chunk = blockIdx.x, cblk = blockIdx.y, cloud = blockIdx.z;
  if (tid < 12) Rts[tid] = Rt[tid];
  __syncthreads();
  const float r0=Rts[0], r1=Rts[1], r2=Rts[2];
  const float r3=Rts[3], r4=Rts[4], r5=Rts[5];
  const float r6=Rts[6], r7=Rts[7], r8=Rts[8];
  const float t0=Rts[9], t1=Rts[10], t2=Rts[11];
  const int j0 = chunk * CHUNK;
  {
    const int jj = j0 + tid;
    float a, b, c;
    if (cloud == 0) {
      float px = in[jj], py = in[NP + jj], pz = in[2*NP + jj];
      a = fmaf(r0, px, fmaf(r1, py, fmaf(r2, pz, t0)));
      b = fmaf(r3, px, fmaf(r4, py, fmaf(r5, pz, t1)));
      c = fmaf(r6, px, fmaf(r7, py, fmaf(r8, pz, t2)));
      if (chunk == cblk) { rx[jj] = a; ry[jj] = b; rz[jj] = c; }
    } else {
      a = ycloud[jj]; b = ycloud[NP + jj]; c = ycloud[2*NP + jj];
    }
    sc[tid] = make_float4(a, b, c, fmaf(a, a, fmaf(b, b, c * c)));
  }
  // center = rigid recon of ci (recomputed, not loaded)
  const int ci = cblk * CHUNK + tid;
  float cx, cy, cz;
  {
    float px = in[ci], py = in[NP + ci], pz = in[2*NP + ci];
    cx = fmaf(r0, px, fmaf(r1, py, fmaf(r2, pz, t0)));
    cy = fmaf(r3, px, fmaf(r4, py, fmaf(r5, pz, t1)));
    cz = fmaf(r6, px, fmaf(r7, py, fmaf(r8, pz, t2)));
  }
  const float ax = -2.f*cx, ay = -2.f*cy, az = -2.f*cz;
  __syncthreads();
  u32 b0=~0u, b1=~0u, b2=~0u, b3=~0u, b4=~0u, b5=~0u;
#pragma unroll 8
  for (int j = 0; j < CHUNK; ++j) {
    float4 c = sc[j];
    float s = fmaf(c.x, ax, fmaf(c.y, ay, fmaf(c.z, az, c.w)));  // |c|^2 - 2c.x
    u32 bits = __float_as_uint(s);
    u32 u = bits ^ ((u32)((int)bits >> 31) | 0x80000000u);       // order-preserving map
    u32 key = (u & 0xFFFFF000u) | (u32)(j0 + j);
    TOP6_INSERT_ILP(key);
  }
  u32* o = part + (size_t)(cloud * NCHUNK + chunk) * KNN * NP + ci;
  o[0*NP] = b0; o[1*NP] = b1; o[2*NP] = b2;
  o[3*NP] = b3; o[4*NP] = b4; o[5*NP] = b5;
}

// K3: 32 blocks (cloud x center-block) fold 16 chunk-lists, gather neighbor
// coords, publish signed f64 block sums via device atomics; the LAST block
// (ticket) computes the mean and the L1 loss. Fixed summation order ->
// bit-deterministic regardless of which block finishes last.
__global__ __launch_bounds__(256) void k3_merge_final(const u32* __restrict__ part,
                                                      const float* __restrict__ rx,
                                                      const float* __restrict__ ry,
                                                      const float* __restrict__ rz,
                                                      const float* __restrict__ ycloud,
                                                      const float* __restrict__ pred,
                                                      double* __restrict__ blockpart,
                                                      u32* __restrict__ counter,
                                                      float* __restrict__ out) {
  const int tid = threadIdx.x;
  const int lane = tid & 63, wv = tid >> 6;
  const int cloud = blockIdx.x >> 4, cblk = blockIdx.x & 15;
  const int ci = cblk * 256 + tid;
  u32 b0=~0u, b1=~0u, b2=~0u, b3=~0u, b4=~0u, b5=~0u;
  for (int c = 0; c < NCHUNK; ++c) {
    const u32* p = part + (size_t)(cloud * NCHUNK + c) * KNN * NP + ci;
#pragma unroll
    for (int e = 0; e < KNN; ++e) {
      u32 key = p[(size_t)e * NP];
      TOP6_INSERT_ILP(key);
    }
  }
  u32 bk[KNN] = { b0, b1, b2, b3, b4, b5 };
  float s0 = 0.f, s1 = 0.f, s2 = 0.f;
  if (cloud == 0) {
#pragma unroll
    for (int k = 0; k < KNN; ++k) {
      int idx = (int)(bk[k] & 0xFFFu);
      s0 += rx[idx]; s1 += ry[idx]; s2 += rz[idx];
    }
  } else {
#pragma unroll
    for (int k = 0; k < KNN; ++k) {
      int idx = (int)(bk[k] & 0xFFFu);
      s0 += ycloud[idx]; s1 += ycloud[NP + idx]; s2 += ycloud[2*NP + idx];
    }
  }
  const double sgn = cloud ? -1.0 : 1.0;
  double v0 = wave_reduce(sgn * (double)s0);
  double v1 = wave_reduce(sgn * (double)s1);
  double v2 = wave_reduce(sgn * (double)s2);
  __shared__ double wred[4][3];
  __shared__ int lastFlag;
  if (lane == 0) { wred[wv][0] = v0; wred[wv][1] = v1; wred[wv][2] = v2; }
  __syncthreads();
  if (tid == 0) {
    for (int q = 0; q < 3; ++q) {
      double B = wred[0][q] + wred[1][q] + wred[2][q] + wred[3][q];
      atomicExch((u64*)&blockpart[blockIdx.x * 3 + q], (u64)__double_as_longlong(B));
    }
    __threadfence();
    u32 t = atomicAdd(counter, 1u);
    lastFlag = (t == 31u);
  }
  __syncthreads();
  if (!lastFlag) return;

  // ---- finisher: mean laplace diff, then L1 loss ----
  __shared__ double bp[96];
  __threadfence();
  if (tid < 96)
    bp[tid] = __longlong_as_double((long long)atomicAdd((u64*)&blockpart[tid], 0ULL));
  __syncthreads();
  __shared__ float m[3];
  if (tid == 0) {
    double a0 = 0.0, a1 = 0.0, a2 = 0.0;
    for (int b = 0; b < 32; ++b) {
      a0 += bp[b*3 + 0]; a1 += bp[b*3 + 1]; a2 += bp[b*3 + 2];
    }
    const double sc = 0.2 / (double)NP;   // /(k-1), then mean over N
    m[0] = (float)(a0 * sc); m[1] = (float)(a1 * sc); m[2] = (float)(a2 * sc);
  }
  __syncthreads();
  const float m0 = m[0], m1 = m[1], m2 = m[2];
  double s = 0.0;
  for (int i = tid; i < NP; i += 256) {
    s += (double)fabsf(rx[i] - m0 - pred[i]);
    s += (double)fabsf(ry[i] - m1 - pred[NP + i]);
    s += (double)fabsf(rz[i] - m2 - pred[2*NP + i]);
  }
  double v = wave_reduce(s);
  __shared__ double fred[4];
  if (lane == 0) fred[wv] = v;
  __syncthreads();
  if (tid == 0)
    out[0] = (float)((fred[0] + fred[1] + fred[2] + fred[3]) / (3.0 * (double)NP));
}

extern "C" void kernel_launch(void* const* d_in, const int* in_sizes, int n_in,
                              void* d_out, int out_size, void* d_ws, size_t ws_size,
                              hipStream_t stream) {
  const float* in   = (const float*)d_in[0];
  const float* sf   = (const float*)d_in[1];
  const float* y1   = (const float*)d_in[2];
  const float* pred = (const float*)d_in[3];

  u32* part = (u32*)d_ws;                                   // 2*16*6*4096 u32 = 3.15 MB
  double* blockpart = (double*)(part + (size_t)2*NCHUNK*KNN*NP);  // 96 doubles (8-aligned)
  u32* counter = (u32*)(blockpart + 96);
  float* Rt = (float*)(counter + 4);                        // 12 floats
  float* rx = Rt + 12;
  float* ry = rx + NP;
  float* rz = ry + NP;

  k1_kabsch<<<1, 256, 0, stream>>>(in, sf, Rt, counter);
  k2_scan<<<dim3(NCHUNK, 16, 2), 256, 0, stream>>>(in, y1, Rt, part, rx, ry, rz);
  k3_merge_final<<<32, 256, 0, stream>>>(part, rx, ry, rz, y1, pred,
                                         blockpart, counter, (float*)d_out);
}